// Round 7
// baseline (337.123 us; speedup 1.0000x reference)
//
#include <hip/hip_runtime.h>

constexpr int N_     = 2048;
constexpr int IN_DIM = 512;
constexpr int HID    = 512;
constexpr int EMB    = 256;
constexpr int M_     = 256;
constexpr int NBLK   = 512;          // grid size == 2 blocks/CU capacity

typedef __attribute__((ext_vector_type(8))) short short8;
typedef __attribute__((ext_vector_type(4))) float f32x4;
typedef __attribute__((ext_vector_type(2))) _Float16 h2v;

#if defined(__has_builtin)
#if __has_builtin(__builtin_amdgcn_fdot2)
#define HAVE_FDOT2 1
#endif
#endif

union U32H2 { unsigned int u; h2v v; };

__device__ __forceinline__ unsigned short f2bf(float f) {
    union { float f; unsigned int u; } v; v.f = f;
    return (unsigned short)((v.u + 0x7fffu + ((v.u >> 16) & 1u)) >> 16);
}
__device__ __forceinline__ unsigned int packh2(float a, float b) {
    U32H2 r; r.v[0] = (_Float16)a; r.v[1] = (_Float16)b; return r.u;
}
__device__ __forceinline__ h2v relu2(h2v s) {
#if defined(__has_builtin) && __has_builtin(__builtin_elementwise_max)
    U32H2 z; z.u = 0u;
    return __builtin_elementwise_max(s, z.v);
#else
    U32H2 t; t.v = s;
    const unsigned int m = ((t.u & 0x80000000u) ? 0xFFFF0000u : 0u) |
                           ((t.u & 0x00008000u) ? 0x0000FFFFu : 0u);
    t.u &= ~m;
    return t.v;
#endif
}

// device-scope grid barrier (all NBLK blocks resident by construction)
__device__ __forceinline__ void gridbar(unsigned int* cnt, int tid) {
    __syncthreads();
    if (tid == 0) {
        __hip_atomic_fetch_add(cnt, 1u, __ATOMIC_ACQ_REL, __HIP_MEMORY_SCOPE_AGENT);
        while (__hip_atomic_load(cnt, __ATOMIC_ACQUIRE, __HIP_MEMORY_SCOPE_AGENT) < (unsigned)NBLK)
            __builtin_amdgcn_s_sleep(2);
    }
    __syncthreads();
}

// ---------------------------------------------------------------------------
// prep unit u (one 256-thread block-unit of work)
// ---------------------------------------------------------------------------
__device__ __forceinline__ void prep_unit(int u, int t,
    const float* __restrict__ x, const float* __restrict__ Wa,
    const float* __restrict__ Wb, const float* __restrict__ W1,
    const int* __restrict__ tuples, const float* __restrict__ Ep,
    const float* __restrict__ Ef, const float* __restrict__ Er,
    const float* __restrict__ w2,
    unsigned short* __restrict__ x_bf, unsigned short* __restrict__ Wa_bf,
    unsigned short* __restrict__ Wb_bf, unsigned short* __restrict__ W1x_bf,
    unsigned short* __restrict__ W1t_bf, unsigned short* __restrict__ t_emb_bf,
    unsigned int* __restrict__ w2p)
{
    if (u < 1664) {
        int q = u * 256 + t;
        float4 v; ushort4 uu;
        if (q < 262144) {                       // x: 2048x512
            v = ((const float4*)x)[q];
            uu.x = f2bf(v.x); uu.y = f2bf(v.y); uu.z = f2bf(v.z); uu.w = f2bf(v.w);
            ((ushort4*)x_bf)[q] = uu;
        } else if ((q -= 262144) < 65536) {     // Wa: 512x512
            v = ((const float4*)Wa)[q];
            uu.x = f2bf(v.x); uu.y = f2bf(v.y); uu.z = f2bf(v.z); uu.w = f2bf(v.w);
            ((ushort4*)Wa_bf)[q] = uu;
        } else if ((q -= 65536) < 32768) {      // Wb: 256x512
            v = ((const float4*)Wb)[q];
            uu.x = f2bf(v.x); uu.y = f2bf(v.y); uu.z = f2bf(v.z); uu.w = f2bf(v.w);
            ((ushort4*)Wb_bf)[q] = uu;
        } else {                                // W1: 512x512 -> W1x | W1t
            q -= 32768;
            v = ((const float4*)W1)[q];
            uu.x = f2bf(v.x); uu.y = f2bf(v.y); uu.z = f2bf(v.z); uu.w = f2bf(v.w);
            const int row = q >> 7, c = (q & 127) * 4;
            if (c < 256) ((ushort4*)W1x_bf)[(row * 256 + c) >> 2] = uu;
            else         ((ushort4*)W1t_bf)[(row * 256 + c - 256) >> 2] = uu;
        }
    } else if (u < 1728) {                      // t_emb gather
        const int idx = (u - 1664) * 256 + t;
        const int m = idx >> 6, q = idx & 63;
        const int t0 = tuples[m * 3 + 0];
        const int t1 = tuples[m * 3 + 1];
        const int t2 = tuples[m * 3 + 2];
        const float4 a = ((const float4*)(Ep + t0 * EMB))[q];
        const float4 c = ((const float4*)(Ef + t1 * EMB))[q];
        const float4 d = ((const float4*)(Er + t2 * EMB))[q];
        ushort4 uu;
        uu.x = f2bf(a.x + c.x + d.x);
        uu.y = f2bf(a.y + c.y + d.y);
        uu.z = f2bf(a.z + c.z + d.z);
        uu.w = f2bf(a.w + c.w + d.w);
        ((ushort4*)t_emb_bf)[m * 64 + q] = uu;
    } else {                                    // w2 -> f16 pairs
        w2p[t] = packh2(w2[2 * t], w2[2 * t + 1]);
    }
}

// ---------------------------------------------------------------------------
// bf16-MFMA NT GEMM stage (bf16 out), double-buffered LDS in smraw.
// ---------------------------------------------------------------------------
template<int BM, int BN, bool RELU, bool BIASC>
__device__ __forceinline__ void gemm_stage(char* smraw, int tid, int bx, int by,
    const unsigned short* __restrict__ A, int lda,
    const unsigned short* __restrict__ W, int ldw,
    const float* __restrict__ bias,
    unsigned short* __restrict__ Cout, int ldc, int K)
{
    constexpr int BK = 64, LDK = 72;
    constexpr int SM = BM / 2, SN = BN / 2;
    constexpr int FM = SM / 16, FN = SN / 16;
    constexpr int AIT = BM / 32, WIT = BN / 32;
    unsigned short* As_ = (unsigned short*)smraw;                  // [2][BM][72]
    unsigned short* Bs_ = (unsigned short*)(smraw + 2 * BM * LDK * 2);

    const int row0 = bx * BM, col0 = by * BN;
    const int wv = tid >> 6, lane = tid & 63;
    const int wr = wv >> 1, wc = wv & 1;
    const int lr = lane & 15, lq = lane >> 4;

    __syncthreads();   // protect LDS reuse across stages/units

    f32x4 acc[FM][FN];
#pragma unroll
    for (int i = 0; i < FM; ++i)
#pragma unroll
        for (int j = 0; j < FN; ++j) acc[i][j] = (f32x4)0.f;

    short8 pa[AIT], pw[WIT];
    auto issue = [&](int k0) {
#pragma unroll
        for (int i = 0; i < AIT; ++i) {
            const int idx = tid + i * 256, r = idx >> 3, c8 = idx & 7;
            pa[i] = *(const short8*)&A[(size_t)(row0 + r) * lda + k0 + c8 * 8];
        }
#pragma unroll
        for (int i = 0; i < WIT; ++i) {
            const int idx = tid + i * 256, r = idx >> 3, c8 = idx & 7;
            pw[i] = *(const short8*)&W[(size_t)(col0 + r) * ldw + k0 + c8 * 8];
        }
    };
    auto store = [&](int bsel) {
#pragma unroll
        for (int i = 0; i < AIT; ++i) {
            const int idx = tid + i * 256, r = idx >> 3, c8 = idx & 7;
            *(short8*)&As_[(bsel * BM + r) * LDK + c8 * 8] = pa[i];
        }
#pragma unroll
        for (int i = 0; i < WIT; ++i) {
            const int idx = tid + i * 256, r = idx >> 3, c8 = idx & 7;
            *(short8*)&Bs_[(bsel * BN + r) * LDK + c8 * 8] = pw[i];
        }
    };

    issue(0); store(0);
    const int NC = K / BK;
    for (int c = 0; c < NC; ++c) {
        const int buf = c & 1;
        __syncthreads();
        if (c + 1 < NC) issue((c + 1) * BK);
#pragma unroll
        for (int ks = 0; ks < 2; ++ks) {
            short8 af[FM], bfr[FN];
#pragma unroll
            for (int i = 0; i < FM; ++i)
                af[i] = *(const short8*)&As_[(buf * BM + wr * SM + i * 16 + lr) * LDK + ks * 32 + lq * 8];
#pragma unroll
            for (int j = 0; j < FN; ++j)
                bfr[j] = *(const short8*)&Bs_[(buf * BN + wc * SN + j * 16 + lr) * LDK + ks * 32 + lq * 8];
#pragma unroll
            for (int i = 0; i < FM; ++i)
#pragma unroll
                for (int j = 0; j < FN; ++j)
                    acc[i][j] = __builtin_amdgcn_mfma_f32_16x16x32_bf16(
                        af[i], bfr[j], acc[i][j], 0, 0, 0);
        }
        if (c + 1 < NC) store((c + 1) & 1);
    }

#pragma unroll
    for (int i = 0; i < FM; ++i) {
#pragma unroll
        for (int j = 0; j < FN; ++j) {
            const int colb = col0 + wc * SN + j * 16 + lr;
#pragma unroll
            for (int e = 0; e < 4; ++e) {
                const int row = row0 + wr * SM + i * 16 + lq * 4 + e;
                float v = acc[i][j][e];
                if (BIASC) v += bias[colb];
                if (RELU)  v = fmaxf(v, 0.f);
                Cout[(size_t)row * ldc + colb] = f2bf(v);
            }
        }
    }
}

// ---------------------------------------------------------------------------
// Dual GEMM stage for hxT/cmT (f16 h-pair-packed out). BM=32, BN=64.
// unit y < 32 -> hxT (B=x_emb); >=32 -> cmT (B=t_emb, +b1).
// ---------------------------------------------------------------------------
__device__ __forceinline__ void gemm_pair_stage(char* smraw, int tid, int bx, int by,
    const unsigned short* __restrict__ W1x_bf,
    const unsigned short* __restrict__ W1t_bf,
    const unsigned short* __restrict__ x_emb_bf,
    const unsigned short* __restrict__ t_emb_bf,
    const float* __restrict__ b1,
    unsigned int* __restrict__ hxT_p,
    unsigned int* __restrict__ cmT_p)
{
    constexpr int BM = 32, BN = 64, BK = 64, LDK = 72;
    constexpr int SM = 16, SN = 32, FN = 2;
    unsigned short* As_ = (unsigned short*)smraw;                  // [2][32][72]
    unsigned short* Bs_ = (unsigned short*)(smraw + 2 * BM * LDK * 2);

    const unsigned short* A; const unsigned short* B;
    const float* bias; unsigned int* outp; int ldc, col0;
    if (by < 32) {
        A = W1x_bf; B = x_emb_bf; bias = nullptr; outp = hxT_p;
        ldc = N_; col0 = by * BN;
    } else {
        A = W1t_bf; B = t_emb_bf; bias = b1; outp = cmT_p;
        ldc = M_; col0 = (by - 32) * BN;
    }
    const int K = EMB, row0 = bx * BM;

    const int wv = tid >> 6, lane = tid & 63;
    const int wr = wv >> 1, wc = wv & 1;
    const int lr = lane & 15, lq = lane >> 4;

    __syncthreads();

    f32x4 acc[FN];
#pragma unroll
    for (int j = 0; j < FN; ++j) acc[j] = (f32x4)0.f;

    short8 pa, pw[2];
    auto issue = [&](int k0) {
        { const int r = tid >> 3, c8 = tid & 7;
          pa = *(const short8*)&A[(size_t)(row0 + r) * K + k0 + c8 * 8]; }
#pragma unroll
        for (int i = 0; i < 2; ++i) {
            const int idx = tid + i * 256, r = idx >> 3, c8 = idx & 7;
            pw[i] = *(const short8*)&B[(size_t)(col0 + r) * K + k0 + c8 * 8];
        }
    };
    auto store = [&](int bsel) {
        { const int r = tid >> 3, c8 = tid & 7;
          *(short8*)&As_[(bsel * BM + r) * LDK + c8 * 8] = pa; }
#pragma unroll
        for (int i = 0; i < 2; ++i) {
            const int idx = tid + i * 256, r = idx >> 3, c8 = idx & 7;
            *(short8*)&Bs_[(bsel * BN + r) * LDK + c8 * 8] = pw[i];
        }
    };

    issue(0); store(0);
    const int NC = K / BK;  // 4
    for (int c = 0; c < NC; ++c) {
        const int buf = c & 1;
        __syncthreads();
        if (c + 1 < NC) issue((c + 1) * BK);
#pragma unroll
        for (int ks = 0; ks < 2; ++ks) {
            short8 af, bfr[FN];
            af = *(const short8*)&As_[(buf * BM + wr * SM + lr) * LDK + ks * 32 + lq * 8];
#pragma unroll
            for (int j = 0; j < FN; ++j)
                bfr[j] = *(const short8*)&Bs_[(buf * BN + wc * SN + j * 16 + lr) * LDK + ks * 32 + lq * 8];
#pragma unroll
            for (int j = 0; j < FN; ++j)
                acc[j] = __builtin_amdgcn_mfma_f32_16x16x32_bf16(af, bfr[j], acc[j], 0, 0, 0);
        }
        if (c + 1 < NC) store((c + 1) & 1);
    }

    const int rowb = row0 + wr * SM + lq * 4;   // multiple of 4
#pragma unroll
    for (int j = 0; j < FN; ++j) {
        const int colb = col0 + wc * SN + j * 16 + lr;
#pragma unroll
        for (int e2 = 0; e2 < 2; ++e2) {
            float v0 = acc[j][2 * e2], v1 = acc[j][2 * e2 + 1];
            if (bias) { v0 += bias[rowb + 2 * e2]; v1 += bias[rowb + 2 * e2 + 1]; }
            outp[(size_t)((rowb >> 1) + e2) * ldc + colb] = packh2(v0, v1);
        }
    }
}

// ---------------------------------------------------------------------------
// fused stage: part[z][n][m] (f16) = sum_{h2 in z} relu(hx+cm) . w2pair
// ---------------------------------------------------------------------------
__device__ __forceinline__ void fused_stage(char* smraw, int tid, int bx, int by, int bz,
    const unsigned int* __restrict__ hxT_p, const unsigned int* __restrict__ cmT_p,
    const unsigned int* __restrict__ w2p, unsigned int* __restrict__ part_u32)
{
    constexpr int TN = 64, TM = 64, H2B = 64, LDT = 68;
    unsigned int* Hs  = (unsigned int*)smraw;       // [64][68]
    unsigned int* Cs  = Hs + H2B * LDT;             // [64][68]
    unsigned int* Wsh = Cs + H2B * LDT;             // [64]

    const int tx = tid & 15, ty = tid >> 4;
    const int n0 = bx * TN, m0 = by * TM, kb = bz * H2B;

    __syncthreads();

#pragma unroll
    for (int p = 0; p < 4; ++p) {
        const int idx = tid + p * 256, r = idx >> 4, c4 = idx & 15;
        *(uint4*)&Hs[r * LDT + c4 * 4] =
            *(const uint4*)&hxT_p[(size_t)(kb + r) * N_ + n0 + c4 * 4];
        *(uint4*)&Cs[r * LDT + c4 * 4] =
            *(const uint4*)&cmT_p[(size_t)(kb + r) * M_ + m0 + c4 * 4];
    }
    if (tid < H2B) Wsh[tid] = w2p[kb + tid];
    __syncthreads();

    float acc[4][4];
#pragma unroll
    for (int i = 0; i < 4; ++i)
#pragma unroll
        for (int j = 0; j < 4; ++j) acc[i][j] = 0.f;

#ifdef HAVE_FDOT2
#pragma unroll 8
    for (int h = 0; h < H2B; ++h) {
        const uint4 av = *(const uint4*)&Hs[h * LDT + ty * 4];
        const uint4 bv = *(const uint4*)&Cs[h * LDT + tx * 4];
        U32H2 w; w.u = Wsh[h];
        U32H2 a[4], b[4];
        a[0].u = av.x; a[1].u = av.y; a[2].u = av.z; a[3].u = av.w;
        b[0].u = bv.x; b[1].u = bv.y; b[2].u = bv.z; b[3].u = bv.w;
#pragma unroll
        for (int i = 0; i < 4; ++i)
#pragma unroll
            for (int j = 0; j < 4; ++j) {
                const h2v s = relu2(a[i].v + b[j].v);
                acc[i][j] = __builtin_amdgcn_fdot2(s, w.v, acc[i][j], false);
            }
    }
#else
    U32H2 facc[4][4];
#pragma unroll
    for (int i = 0; i < 4; ++i)
#pragma unroll
        for (int j = 0; j < 4; ++j) facc[i][j].u = 0u;
#pragma unroll
    for (int hb = 0; hb < H2B / 8; ++hb) {
#pragma unroll
        for (int hh = 0; hh < 8; ++hh) {
            const int h = hb * 8 + hh;
            const uint4 av = *(const uint4*)&Hs[h * LDT + ty * 4];
            const uint4 bv = *(const uint4*)&Cs[h * LDT + tx * 4];
            U32H2 w; w.u = Wsh[h];
            U32H2 a[4], b[4];
            a[0].u = av.x; a[1].u = av.y; a[2].u = av.z; a[3].u = av.w;
            b[0].u = bv.x; b[1].u = bv.y; b[2].u = bv.z; b[3].u = bv.w;
#pragma unroll
            for (int i = 0; i < 4; ++i)
#pragma unroll
                for (int j = 0; j < 4; ++j) {
                    const h2v s = relu2(a[i].v + b[j].v);
                    facc[i][j].v = s * w.v + facc[i][j].v;
                }
        }
#pragma unroll
        for (int i = 0; i < 4; ++i)
#pragma unroll
            for (int j = 0; j < 4; ++j) {
                acc[i][j] += (float)facc[i][j].v[0] + (float)facc[i][j].v[1];
                facc[i][j].u = 0u;
            }
    }
#endif

#pragma unroll
    for (int i = 0; i < 4; ++i) {
        const int n = n0 + ty * 4 + i;
        const size_t base = ((size_t)bz * N_ + n) * (M_ / 2) + (m0 >> 1) + tx * 2;
        part_u32[base]     = packh2(acc[i][0], acc[i][1]);
        part_u32[base + 1] = packh2(acc[i][2], acc[i][3]);
    }
}

// ---------------------------------------------------------------------------
// reduce unit: out[n,m] = b2 + sum_z part[z][n][m]
// ---------------------------------------------------------------------------
__device__ __forceinline__ void reduce_unit(int bid, int tid,
    const unsigned short* __restrict__ part, const float* __restrict__ b2,
    float* __restrict__ out)
{
    const int g = bid * 256 + tid;   // 65536
    const int n = g >> 5;
    const int m0 = (g & 31) * 8;
    const float bb = b2[0];
    float s[8];
#pragma unroll
    for (int i = 0; i < 8; ++i) s[i] = bb;
#pragma unroll
    for (int zz = 0; zz < 4; ++zz) {
        const uint4 v = *(const uint4*)&part[((size_t)zz * N_ + n) * M_ + m0];
        const unsigned int vv[4] = {v.x, v.y, v.z, v.w};
#pragma unroll
        for (int q = 0; q < 4; ++q) {
            U32H2 u; u.u = vv[q];
            s[2 * q]     += (float)u.v[0];
            s[2 * q + 1] += (float)u.v[1];
        }
    }
    float4 o0 = {s[0], s[1], s[2], s[3]};
    float4 o1 = {s[4], s[5], s[6], s[7]};
    *(float4*)&out[(size_t)n * M_ + m0]     = o0;
    *(float4*)&out[(size_t)n * M_ + m0 + 4] = o1;
}

// ---------------------------------------------------------------------------
// The single persistent kernel. 512 blocks x 256 threads, all co-resident.
// ---------------------------------------------------------------------------
__global__ __launch_bounds__(256, 2)
void mega(const float* __restrict__ x, const int* __restrict__ tuples,
          const float* __restrict__ Wa, const float* __restrict__ ba,
          const float* __restrict__ Wb, const float* __restrict__ bb,
          const float* __restrict__ Ep, const float* __restrict__ Ef,
          const float* __restrict__ Er, const float* __restrict__ W1,
          const float* __restrict__ b1, const float* __restrict__ w2,
          const float* __restrict__ b2, float* __restrict__ out,
          char* __restrict__ w)
{
    __shared__ __align__(16) char smraw[35072];
    const int tid = threadIdx.x, bid = blockIdx.x;

    unsigned short* x_bf     = (unsigned short*)(w + 0);
    unsigned int*   hxT_p    = (unsigned int*)(w + 0);
    unsigned short* h_x_bf   = (unsigned short*)(w + 2097152);
    unsigned int*   part_u32 = (unsigned int*)(w + 2097152);
    unsigned short* x_emb_bf = (unsigned short*)(w + 4194304);
    unsigned short* Wa_bf    = (unsigned short*)(w + 5242880);
    unsigned short* Wb_bf    = (unsigned short*)(w + 5767168);
    unsigned short* W1x_bf   = (unsigned short*)(w + 6029312);
    unsigned int*   cmT_p    = (unsigned int*)(w + 6291456);
    unsigned short* W1t_bf   = (unsigned short*)(w + 6553600);
    unsigned short* t_emb_bf = (unsigned short*)(w + 6815744);
    unsigned int*   w2p      = (unsigned int*)(w + 6946816);
    unsigned int*   bar      = (unsigned int*)(w + 7340032);  // cnt[8] + flag

    // init gate (ws is poisoned 0xAA every launch)
    if (bid == 0 && tid == 0) {
        for (int i = 0; i < 8; ++i)
            __hip_atomic_store(&bar[i], 0u, __ATOMIC_RELAXED, __HIP_MEMORY_SCOPE_AGENT);
        __hip_atomic_store(&bar[8], 0x13579BDFu, __ATOMIC_RELEASE, __HIP_MEMORY_SCOPE_AGENT);
    }
    if (tid == 0) {
        while (__hip_atomic_load(&bar[8], __ATOMIC_ACQUIRE, __HIP_MEMORY_SCOPE_AGENT) != 0x13579BDFu)
            __builtin_amdgcn_s_sleep(2);
    }
    __syncthreads();

    // stage P: prep (1729 units)
    for (int u = bid; u < 1729; u += NBLK)
        prep_unit(u, tid, x, Wa, Wb, W1, tuples, Ep, Ef, Er, w2,
                  x_bf, Wa_bf, Wb_bf, W1x_bf, W1t_bf, t_emb_bf, w2p);
    gridbar(&bar[0], tid);

    // stage 1: h_x = relu(x @ Wa^T + ba)   (2048x512, K=512), 64x8 tiles
    gemm_stage<32, 64, true, true>(smraw, tid, bid & 63, bid >> 6,
        x_bf, IN_DIM, Wa_bf, IN_DIM, ba, h_x_bf, HID, IN_DIM);
    gridbar(&bar[1], tid);

    // stage 2: x_emb = relu(h_x @ Wb^T + bb)  (2048x256, K=512), 64x8 tiles
    gemm_stage<32, 32, true, true>(smraw, tid, bid & 63, bid >> 6,
        h_x_bf, HID, Wb_bf, HID, bb, x_emb_bf, EMB, HID);
    gridbar(&bar[2], tid);

    // stage 3: hxT_p / cmT_p (576 units of 32x64)
    for (int u = bid; u < 576; u += NBLK)
        gemm_pair_stage(smraw, tid, u & 15, u >> 4,
            W1x_bf, W1t_bf, x_emb_bf, t_emb_bf, b1, hxT_p, cmT_p);
    gridbar(&bar[3], tid);

    // stage 4: fused partials (32 x 4 x 4 tiles)
    fused_stage(smraw, tid, bid & 31, (bid >> 5) & 3, bid >> 7,
                hxT_p, cmT_p, w2p, part_u32);
    gridbar(&bar[4], tid);

    // stage 5: reduce (256 units)
    if (bid < 256)
        reduce_unit(bid, tid, (const unsigned short*)part_u32, b2, out);
}

// ---------------------------------------------------------------------------
extern "C" void kernel_launch(void* const* d_in, const int* in_sizes, int n_in,
                              void* d_out, int out_size, void* d_ws, size_t ws_size,
                              hipStream_t stream)
{
    const float* x      = (const float*)d_in[0];
    const int*   tuples = (const int*)d_in[1];
    const float* Wa     = (const float*)d_in[2];
    const float* ba     = (const float*)d_in[3];
    const float* Wb     = (const float*)d_in[4];
    const float* bb     = (const float*)d_in[5];
    const float* E_pred = (const float*)d_in[6];
    const float* E_filt = (const float*)d_in[7];
    const float* E_reo  = (const float*)d_in[8];
    const float* W1     = (const float*)d_in[9];
    const float* b1     = (const float*)d_in[10];
    const float* W2     = (const float*)d_in[11];
    const float* b2     = (const float*)d_in[12];

    mega<<<dim3(NBLK), dim3(256), 0, stream>>>(
        x, tuples, Wa, ba, Wb, bb, E_pred, E_filt, E_reo, W1, b1, W2, b2,
        (float*)d_out, (char*)d_ws);
}

// Round 8
// 139.759 us; speedup vs baseline: 2.4122x; 2.4122x over previous
//
#include <hip/hip_runtime.h>

constexpr int N_     = 2048;
constexpr int IN_DIM = 512;
constexpr int HID    = 512;
constexpr int EMB    = 256;
constexpr int M_     = 256;

typedef __attribute__((ext_vector_type(8))) short short8;
typedef __attribute__((ext_vector_type(4))) float f32x4;
typedef __attribute__((ext_vector_type(2))) _Float16 h2v;

#if defined(__has_builtin)
#if __has_builtin(__builtin_amdgcn_fdot2)
#define HAVE_FDOT2 1
#endif
#endif

union U32H2 { unsigned int u; h2v v; };

__device__ __forceinline__ unsigned short f2bf(float f) {
    union { float f; unsigned int u; } v; v.f = f;
    return (unsigned short)((v.u + 0x7fffu + ((v.u >> 16) & 1u)) >> 16);
}
__device__ __forceinline__ unsigned int packh2(float a, float b) {
    U32H2 r; r.v[0] = (_Float16)a; r.v[1] = (_Float16)b; return r.u;
}
__device__ __forceinline__ h2v relu2(h2v s) {
#if defined(__has_builtin) && __has_builtin(__builtin_elementwise_max)
    U32H2 z; z.u = 0u;
    return __builtin_elementwise_max(s, z.v);
#else
    U32H2 t; t.v = s;
    const unsigned int m = ((t.u & 0x80000000u) ? 0xFFFF0000u : 0u) |
                           ((t.u & 0x00008000u) ? 0x0000FFFFu : 0u);
    t.u &= ~m;
    return t.v;
#endif
}

// ---------------------------------------------------------------------------
// prep: fp32->bf16 of x,Wa,Wb,W1(split) + t_emb gather (bf16) + w2 f16-pairs.
// ---------------------------------------------------------------------------
__global__ __launch_bounds__(256)
void prep(const float* __restrict__ x, const float* __restrict__ Wa,
          const float* __restrict__ Wb, const float* __restrict__ W1,
          const int* __restrict__ tuples, const float* __restrict__ Ep,
          const float* __restrict__ Ef, const float* __restrict__ Er,
          const float* __restrict__ w2,
          unsigned short* __restrict__ x_bf, unsigned short* __restrict__ Wa_bf,
          unsigned short* __restrict__ Wb_bf, unsigned short* __restrict__ W1x_bf,
          unsigned short* __restrict__ W1t_bf, unsigned short* __restrict__ t_emb_bf,
          unsigned int* __restrict__ w2p)
{
    const int b = blockIdx.x, t = threadIdx.x;
    if (b < 1664) {
        int q = b * 256 + t;
        float4 v; ushort4 u;
        if (q < 262144) {                       // x: 2048x512
            v = ((const float4*)x)[q];
            u.x = f2bf(v.x); u.y = f2bf(v.y); u.z = f2bf(v.z); u.w = f2bf(v.w);
            ((ushort4*)x_bf)[q] = u;
        } else if ((q -= 262144) < 65536) {     // Wa: 512x512
            v = ((const float4*)Wa)[q];
            u.x = f2bf(v.x); u.y = f2bf(v.y); u.z = f2bf(v.z); u.w = f2bf(v.w);
            ((ushort4*)Wa_bf)[q] = u;
        } else if ((q -= 65536) < 32768) {      // Wb: 256x512
            v = ((const float4*)Wb)[q];
            u.x = f2bf(v.x); u.y = f2bf(v.y); u.z = f2bf(v.z); u.w = f2bf(v.w);
            ((ushort4*)Wb_bf)[q] = u;
        } else {                                // W1: 512x512 -> W1x | W1t
            q -= 32768;
            v = ((const float4*)W1)[q];
            u.x = f2bf(v.x); u.y = f2bf(v.y); u.z = f2bf(v.z); u.w = f2bf(v.w);
            const int row = q >> 7, c = (q & 127) * 4;
            if (c < 256) ((ushort4*)W1x_bf)[(row * 256 + c) >> 2] = u;
            else         ((ushort4*)W1t_bf)[(row * 256 + c - 256) >> 2] = u;
        }
    } else if (b < 1728) {                      // t_emb gather
        const int idx = (b - 1664) * 256 + t;   // 0..16383
        const int m = idx >> 6, q = idx & 63;
        const int t0 = tuples[m * 3 + 0];
        const int t1 = tuples[m * 3 + 1];
        const int t2 = tuples[m * 3 + 2];
        const float4 a = ((const float4*)(Ep + t0 * EMB))[q];
        const float4 c = ((const float4*)(Ef + t1 * EMB))[q];
        const float4 d = ((const float4*)(Er + t2 * EMB))[q];
        ushort4 u;
        u.x = f2bf(a.x + c.x + d.x);
        u.y = f2bf(a.y + c.y + d.y);
        u.z = f2bf(a.z + c.z + d.z);
        u.w = f2bf(a.w + c.w + d.w);
        ((ushort4*)t_emb_bf)[m * 64 + q] = u;
    } else {                                    // w2 -> f16 pairs (256)
        w2p[t] = packh2(w2[2 * t], w2[2 * t + 1]);
    }
}

// ---------------------------------------------------------------------------
// bf16-MFMA NT GEMM (bf16 out), BK=128: double-buffered LDS, one barrier per
// 128-deep K-chunk (8-16 MFMA between barriers).
// ---------------------------------------------------------------------------
template<int BM, int BN, bool RELU, bool BIASC>
__global__ __launch_bounds__(256, 2)
void gemm_bf16(const unsigned short* __restrict__ A, int lda,
               const unsigned short* __restrict__ W, int ldw,
               const float* __restrict__ bias,
               unsigned short* __restrict__ Cout, int ldc, int K)
{
    constexpr int BK = 128, LDK = BK + 8;
    constexpr int SM = BM / 2, SN = BN / 2;
    constexpr int FM = SM / 16, FN = SN / 16;
    constexpr int AIT = BM / 16, WIT = BN / 16;     // (BM*BK/8)/256
    __shared__ unsigned short As[2][BM][LDK];
    __shared__ unsigned short Bs[2][BN][LDK];

    const int tid  = threadIdx.x;
    const int row0 = blockIdx.x * BM, col0 = blockIdx.y * BN;
    const int wv = tid >> 6, lane = tid & 63;
    const int wr = wv >> 1, wc = wv & 1;
    const int lr = lane & 15, lq = lane >> 4;

    f32x4 acc[FM][FN];
#pragma unroll
    for (int i = 0; i < FM; ++i)
#pragma unroll
        for (int j = 0; j < FN; ++j) acc[i][j] = (f32x4)0.f;

    short8 pa[AIT], pw[WIT];
    auto issue = [&](int k0) {
#pragma unroll
        for (int i = 0; i < AIT; ++i) {
            const int idx = tid + i * 256, r = idx >> 4, c8 = idx & 15;
            pa[i] = *(const short8*)&A[(size_t)(row0 + r) * lda + k0 + c8 * 8];
        }
#pragma unroll
        for (int i = 0; i < WIT; ++i) {
            const int idx = tid + i * 256, r = idx >> 4, c8 = idx & 15;
            pw[i] = *(const short8*)&W[(size_t)(col0 + r) * ldw + k0 + c8 * 8];
        }
    };
    auto store = [&](int bsel) {
#pragma unroll
        for (int i = 0; i < AIT; ++i) {
            const int idx = tid + i * 256, r = idx >> 4, c8 = idx & 15;
            *(short8*)&As[bsel][r][c8 * 8] = pa[i];
        }
#pragma unroll
        for (int i = 0; i < WIT; ++i) {
            const int idx = tid + i * 256, r = idx >> 4, c8 = idx & 15;
            *(short8*)&Bs[bsel][r][c8 * 8] = pw[i];
        }
    };

    issue(0); store(0);
    const int NC = K / BK;
    for (int c = 0; c < NC; ++c) {
        const int buf = c & 1;
        __syncthreads();
        if (c + 1 < NC) issue((c + 1) * BK);
#pragma unroll
        for (int ks = 0; ks < BK / 32; ++ks) {
            short8 af[FM], bfr[FN];
#pragma unroll
            for (int i = 0; i < FM; ++i)
                af[i] = *(const short8*)&As[buf][wr * SM + i * 16 + lr][ks * 32 + lq * 8];
#pragma unroll
            for (int j = 0; j < FN; ++j)
                bfr[j] = *(const short8*)&Bs[buf][wc * SN + j * 16 + lr][ks * 32 + lq * 8];
#pragma unroll
            for (int i = 0; i < FM; ++i)
#pragma unroll
                for (int j = 0; j < FN; ++j)
                    acc[i][j] = __builtin_amdgcn_mfma_f32_16x16x32_bf16(
                        af[i], bfr[j], acc[i][j], 0, 0, 0);
        }
        if (c + 1 < NC) store((c + 1) & 1);
    }

#pragma unroll
    for (int i = 0; i < FM; ++i) {
#pragma unroll
        for (int j = 0; j < FN; ++j) {
            const int colb = col0 + wc * SN + j * 16 + lr;
#pragma unroll
            for (int e = 0; e < 4; ++e) {
                const int row = row0 + wr * SM + i * 16 + lq * 4 + e;
                float v = acc[i][j][e];
                if (BIASC) v += bias[colb];
                if (RELU)  v = fmaxf(v, 0.f);
                Cout[(size_t)row * ldc + colb] = f2bf(v);
            }
        }
    }
}

// ---------------------------------------------------------------------------
// Dual GEMM for hxT/cmT (f16 h-pair-packed out), BK=128 double-buffered.
// blockIdx.y < 32 -> hxT (B=x_emb);  >=32 -> cmT (B=t_emb, +b1).
// ---------------------------------------------------------------------------
__global__ __launch_bounds__(256, 2)
void gemm_pair(const unsigned short* __restrict__ W1x_bf,
               const unsigned short* __restrict__ W1t_bf,
               const unsigned short* __restrict__ x_emb_bf,
               const unsigned short* __restrict__ t_emb_bf,
               const float* __restrict__ b1,
               unsigned int* __restrict__ hxT_p,
               unsigned int* __restrict__ cmT_p)
{
    constexpr int BM = 32, BN = 64, BK = 128, LDK = BK + 8;
    constexpr int SM = 16, SN = 32, FN = 2;
    __shared__ unsigned short As[2][BM][LDK];
    __shared__ unsigned short Bs[2][BN][LDK];

    const unsigned short* A; const unsigned short* B;
    const float* bias; unsigned int* outp; int ldc, col0;
    if (blockIdx.y < 32) {
        A = W1x_bf; B = x_emb_bf; bias = nullptr; outp = hxT_p;
        ldc = N_; col0 = blockIdx.y * BN;
    } else {
        A = W1t_bf; B = t_emb_bf; bias = b1; outp = cmT_p;
        ldc = M_; col0 = (blockIdx.y - 32) * BN;
    }
    const int K = EMB, row0 = blockIdx.x * BM;

    const int tid = threadIdx.x;
    const int wv = tid >> 6, lane = tid & 63;
    const int wr = wv >> 1, wc = wv & 1;
    const int lr = lane & 15, lq = lane >> 4;

    f32x4 acc[FN];
#pragma unroll
    for (int j = 0; j < FN; ++j) acc[j] = (f32x4)0.f;

    short8 pa[2], pw[4];
    auto issue = [&](int k0) {
#pragma unroll
        for (int i = 0; i < 2; ++i) {
            const int idx = tid + i * 256, r = idx >> 4, c8 = idx & 15;
            pa[i] = *(const short8*)&A[(size_t)(row0 + r) * K + k0 + c8 * 8];
        }
#pragma unroll
        for (int i = 0; i < 4; ++i) {
            const int idx = tid + i * 256, r = idx >> 4, c8 = idx & 15;
            pw[i] = *(const short8*)&B[(size_t)(col0 + r) * K + k0 + c8 * 8];
        }
    };
    auto store = [&](int bsel) {
#pragma unroll
        for (int i = 0; i < 2; ++i) {
            const int idx = tid + i * 256, r = idx >> 4, c8 = idx & 15;
            *(short8*)&As[bsel][r][c8 * 8] = pa[i];
        }
#pragma unroll
        for (int i = 0; i < 4; ++i) {
            const int idx = tid + i * 256, r = idx >> 4, c8 = idx & 15;
            *(short8*)&Bs[bsel][r][c8 * 8] = pw[i];
        }
    };

    issue(0); store(0);
    const int NC = K / BK;  // 2
    for (int c = 0; c < NC; ++c) {
        const int buf = c & 1;
        __syncthreads();
        if (c + 1 < NC) issue((c + 1) * BK);
#pragma unroll
        for (int ks = 0; ks < BK / 32; ++ks) {
            short8 af, bfr[FN];
            af = *(const short8*)&As[buf][wr * SM + lr][ks * 32 + lq * 8];
#pragma unroll
            for (int j = 0; j < FN; ++j)
                bfr[j] = *(const short8*)&Bs[buf][wc * SN + j * 16 + lr][ks * 32 + lq * 8];
#pragma unroll
            for (int j = 0; j < FN; ++j)
                acc[j] = __builtin_amdgcn_mfma_f32_16x16x32_bf16(af, bfr[j], acc[j], 0, 0, 0);
        }
        if (c + 1 < NC) store((c + 1) & 1);
    }

    const int rowb = row0 + wr * SM + lq * 4;   // multiple of 4
#pragma unroll
    for (int j = 0; j < FN; ++j) {
        const int colb = col0 + wc * SN + j * 16 + lr;
#pragma unroll
        for (int e2 = 0; e2 < 2; ++e2) {
            float v0 = acc[j][2 * e2], v1 = acc[j][2 * e2 + 1];
            if (bias) { v0 += bias[rowb + 2 * e2]; v1 += bias[rowb + 2 * e2 + 1]; }
            outp[(size_t)((rowb >> 1) + e2) * ldc + colb] = packh2(v0, v1);
        }
    }
}

// ---------------------------------------------------------------------------
// out[n,m] += sum_{h2 in z} relu(hx_pair + cm_pair) . w2_pair  (+b2 at z=0)
// Tile 64n x 64m, z=4, 512 blocks, fp32 atomicAdd to memset-zeroed out.
// ---------------------------------------------------------------------------
__global__ __launch_bounds__(256, 2)
void fused_out(const unsigned int* __restrict__ hxT_p,   // [256][2048]
               const unsigned int* __restrict__ cmT_p,   // [256][256]
               const unsigned int* __restrict__ w2p,     // [256]
               const float* __restrict__ b2,
               float* __restrict__ out)
{
    constexpr int TN = 64, TM = 64, H2B = 64, LDT = 68;
    __shared__ unsigned int Hs[H2B][LDT];
    __shared__ unsigned int Cs[H2B][LDT];
    __shared__ unsigned int Wsh[H2B];

    const int tid = threadIdx.x;
    const int tx = tid & 15, ty = tid >> 4;
    const int n0 = blockIdx.x * TN;
    const int m0 = blockIdx.y * TM;
    const int kb = blockIdx.z * H2B;

#pragma unroll
    for (int p = 0; p < 4; ++p) {
        const int idx = tid + p * 256, r = idx >> 4, c4 = idx & 15;
        *(uint4*)&Hs[r][c4 * 4] =
            *(const uint4*)&hxT_p[(size_t)(kb + r) * N_ + n0 + c4 * 4];
        *(uint4*)&Cs[r][c4 * 4] =
            *(const uint4*)&cmT_p[(size_t)(kb + r) * M_ + m0 + c4 * 4];
    }
    if (tid < H2B) Wsh[tid] = w2p[kb + tid];
    __syncthreads();

    float acc[4][4];
#pragma unroll
    for (int i = 0; i < 4; ++i)
#pragma unroll
        for (int j = 0; j < 4; ++j) acc[i][j] = 0.f;

#ifdef HAVE_FDOT2
#pragma unroll 8
    for (int h = 0; h < H2B; ++h) {
        const uint4 av = *(const uint4*)&Hs[h][ty * 4];
        const uint4 bv = *(const uint4*)&Cs[h][tx * 4];
        U32H2 w; w.u = Wsh[h];
        U32H2 a[4], b[4];
        a[0].u = av.x; a[1].u = av.y; a[2].u = av.z; a[3].u = av.w;
        b[0].u = bv.x; b[1].u = bv.y; b[2].u = bv.z; b[3].u = bv.w;
#pragma unroll
        for (int i = 0; i < 4; ++i)
#pragma unroll
            for (int j = 0; j < 4; ++j) {
                const h2v s = relu2(a[i].v + b[j].v);
                acc[i][j] = __builtin_amdgcn_fdot2(s, w.v, acc[i][j], false);
            }
    }
#else
    U32H2 facc[4][4];
#pragma unroll
    for (int i = 0; i < 4; ++i)
#pragma unroll
        for (int j = 0; j < 4; ++j) facc[i][j].u = 0u;
#pragma unroll
    for (int hb = 0; hb < H2B / 8; ++hb) {
#pragma unroll
        for (int hh = 0; hh < 8; ++hh) {
            const int h = hb * 8 + hh;
            const uint4 av = *(const uint4*)&Hs[h][ty * 4];
            const uint4 bv = *(const uint4*)&Cs[h][tx * 4];
            U32H2 w; w.u = Wsh[h];
            U32H2 a[4], b[4];
            a[0].u = av.x; a[1].u = av.y; a[2].u = av.z; a[3].u = av.w;
            b[0].u = bv.x; b[1].u = bv.y; b[2].u = bv.z; b[3].u = bv.w;
#pragma unroll
            for (int i = 0; i < 4; ++i)
#pragma unroll
                for (int j = 0; j < 4; ++j) {
                    const h2v s = relu2(a[i].v + b[j].v);
                    facc[i][j].v = s * w.v + facc[i][j].v;
                }
        }
#pragma unroll
        for (int i = 0; i < 4; ++i)
#pragma unroll
            for (int j = 0; j < 4; ++j) {
                acc[i][j] += (float)facc[i][j].v[0] + (float)facc[i][j].v[1];
                facc[i][j].u = 0u;
            }
    }
#endif

    const float bb = (blockIdx.z == 0) ? b2[0] : 0.f;
#pragma unroll
    for (int i = 0; i < 4; ++i) {
        const int n = n0 + ty * 4 + i;
#pragma unroll
        for (int j = 0; j < 4; ++j)
            atomicAdd(&out[(size_t)n * M_ + m0 + tx * 4 + j], acc[i][j] + bb);
    }
}

// ---------------------------------------------------------------------------
extern "C" void kernel_launch(void* const* d_in, const int* in_sizes, int n_in,
                              void* d_out, int out_size, void* d_ws, size_t ws_size,
                              hipStream_t stream)
{
    const float* x      = (const float*)d_in[0];
    const int*   tuples = (const int*)d_in[1];
    const float* Wa     = (const float*)d_in[2];
    const float* ba     = (const float*)d_in[3];
    const float* Wb     = (const float*)d_in[4];
    const float* bb     = (const float*)d_in[5];
    const float* E_pred = (const float*)d_in[6];
    const float* E_filt = (const float*)d_in[7];
    const float* E_reo  = (const float*)d_in[8];
    const float* W1     = (const float*)d_in[9];
    const float* b1     = (const float*)d_in[10];
    const float* W2     = (const float*)d_in[11];
    const float* b2     = (const float*)d_in[12];
    float* out = (float*)d_out;

    // ws layout (byte offsets), peak ~6.63 MB:
    char* w = (char*)d_ws;
    unsigned short* x_bf     = (unsigned short*)(w + 0);
    unsigned int*   hxT_p    = (unsigned int*)(w + 0);
    unsigned short* h_x_bf   = (unsigned short*)(w + 2097152);
    unsigned short* x_emb_bf = (unsigned short*)(w + 4194304);
    unsigned short* Wa_bf    = (unsigned short*)(w + 5242880);
    unsigned short* Wb_bf    = (unsigned short*)(w + 5767168);
    unsigned short* W1x_bf   = (unsigned short*)(w + 6029312);
    unsigned int*   cmT_p    = (unsigned int*)(w + 6291456);
    unsigned short* W1t_bf   = (unsigned short*)(w + 6553600);
    unsigned short* t_emb_bf = (unsigned short*)(w + 6815744);
    unsigned int*   w2p      = (unsigned int*)(w + 6946816);

    hipMemsetAsync(d_out, 0, (size_t)N_ * M_ * sizeof(float), stream);

    prep<<<dim3(1729), dim3(256), 0, stream>>>(
        x, Wa, Wb, W1, tuples, E_pred, E_filt, E_reo, W2,
        x_bf, Wa_bf, Wb_bf, W1x_bf, W1t_bf, t_emb_bf, w2p);

    // h_x = relu(x @ Wa^T + ba)   (2048x512, K=512) grid 64x8
    gemm_bf16<32, 64, true, true><<<dim3(N_ / 32, HID / 64), 256, 0, stream>>>(
        x_bf, IN_DIM, Wa_bf, IN_DIM, ba, h_x_bf, HID, IN_DIM);

    // x_emb = relu(h_x @ Wb^T + bb)  (2048x256, K=512) grid 64x8
    gemm_bf16<32, 32, true, true><<<dim3(N_ / 32, EMB / 32), 256, 0, stream>>>(
        h_x_bf, HID, Wb_bf, HID, bb, x_emb_bf, EMB, HID);

    // hxT_p[h2][n] & cmT_p[h2][m] (f16 h-pairs), merged: grid 16 x (32+4)
    gemm_pair<<<dim3(HID / 32, 36), 256, 0, stream>>>(
        W1x_bf, W1t_bf, x_emb_bf, t_emb_bf, b1, hxT_p, cmT_p);

    // out += partials over z=4 h-slices (+ b2 at z=0), 64x64 tiles
    fused_out<<<dim3(N_ / 64, M_ / 64, 4), 256, 0, stream>>>(
        hxT_p, cmT_p, w2p, b2, out);
}

// Round 9
// 115.193 us; speedup vs baseline: 2.9266x; 1.2133x over previous
//
#include <hip/hip_runtime.h>

constexpr int N_     = 2048;
constexpr int IN_DIM = 512;
constexpr int HID    = 512;
constexpr int EMB    = 256;
constexpr int M_     = 256;

typedef __attribute__((ext_vector_type(8))) short short8;
typedef __attribute__((ext_vector_type(4))) float f32x4;
typedef __attribute__((ext_vector_type(2))) _Float16 h2v;

#if defined(__has_builtin)
#if __has_builtin(__builtin_amdgcn_fdot2)
#define HAVE_FDOT2 1
#endif
#endif

union U32H2 { unsigned int u; h2v v; };

__device__ __forceinline__ unsigned short f2bf(float f) {
    union { float f; unsigned int u; } v; v.f = f;
    return (unsigned short)((v.u + 0x7fffu + ((v.u >> 16) & 1u)) >> 16);
}
__device__ __forceinline__ unsigned int packh2(float a, float b) {
    U32H2 r; r.v[0] = (_Float16)a; r.v[1] = (_Float16)b; return r.u;
}
__device__ __forceinline__ h2v relu2(h2v s) {
#if defined(__has_builtin) && __has_builtin(__builtin_elementwise_max)
    U32H2 z; z.u = 0u;
    return __builtin_elementwise_max(s, z.v);
#else
    U32H2 t; t.v = s;
    const unsigned int m = ((t.u & 0x80000000u) ? 0xFFFF0000u : 0u) |
                           ((t.u & 0x00008000u) ? 0x0000FFFFu : 0u);
    t.u &= ~m;
    return t.v;
#endif
}

// ---------------------------------------------------------------------------
// prep: fp32->bf16 of x,Wa,Wb,W1(split) + t_emb gather (bf16) + w2 f16-pairs.
// ---------------------------------------------------------------------------
__global__ __launch_bounds__(256)
void prep(const float* __restrict__ x, const float* __restrict__ Wa,
          const float* __restrict__ Wb, const float* __restrict__ W1,
          const int* __restrict__ tuples, const float* __restrict__ Ep,
          const float* __restrict__ Ef, const float* __restrict__ Er,
          const float* __restrict__ w2,
          unsigned short* __restrict__ x_bf, unsigned short* __restrict__ Wa_bf,
          unsigned short* __restrict__ Wb_bf, unsigned short* __restrict__ W1x_bf,
          unsigned short* __restrict__ W1t_bf, unsigned short* __restrict__ t_emb_bf,
          unsigned int* __restrict__ w2p)
{
    const int b = blockIdx.x, t = threadIdx.x;
    if (b < 1664) {
        int q = b * 256 + t;
        float4 v; ushort4 u;
        if (q < 262144) {                       // x: 2048x512
            v = ((const float4*)x)[q];
            u.x = f2bf(v.x); u.y = f2bf(v.y); u.z = f2bf(v.z); u.w = f2bf(v.w);
            ((ushort4*)x_bf)[q] = u;
        } else if ((q -= 262144) < 65536) {     // Wa: 512x512
            v = ((const float4*)Wa)[q];
            u.x = f2bf(v.x); u.y = f2bf(v.y); u.z = f2bf(v.z); u.w = f2bf(v.w);
            ((ushort4*)Wa_bf)[q] = u;
        } else if ((q -= 65536) < 32768) {      // Wb: 256x512
            v = ((const float4*)Wb)[q];
            u.x = f2bf(v.x); u.y = f2bf(v.y); u.z = f2bf(v.z); u.w = f2bf(v.w);
            ((ushort4*)Wb_bf)[q] = u;
        } else {                                // W1: 512x512 -> W1x | W1t
            q -= 32768;
            v = ((const float4*)W1)[q];
            u.x = f2bf(v.x); u.y = f2bf(v.y); u.z = f2bf(v.z); u.w = f2bf(v.w);
            const int row = q >> 7, c = (q & 127) * 4;
            if (c < 256) ((ushort4*)W1x_bf)[(row * 256 + c) >> 2] = u;
            else         ((ushort4*)W1t_bf)[(row * 256 + c - 256) >> 2] = u;
        }
    } else if (b < 1728) {                      // t_emb gather
        const int idx = (b - 1664) * 256 + t;   // 0..16383
        const int m = idx >> 6, q = idx & 63;
        const int t0 = tuples[m * 3 + 0];
        const int t1 = tuples[m * 3 + 1];
        const int t2 = tuples[m * 3 + 2];
        const float4 a = ((const float4*)(Ep + t0 * EMB))[q];
        const float4 c = ((const float4*)(Ef + t1 * EMB))[q];
        const float4 d = ((const float4*)(Er + t2 * EMB))[q];
        ushort4 u;
        u.x = f2bf(a.x + c.x + d.x);
        u.y = f2bf(a.y + c.y + d.y);
        u.z = f2bf(a.z + c.z + d.z);
        u.w = f2bf(a.w + c.w + d.w);
        ((ushort4*)t_emb_bf)[m * 64 + q] = u;
    } else {                                    // w2 -> f16 pairs (256)
        w2p[t] = packh2(w2[2 * t], w2[2 * t + 1]);
    }
}

// ---------------------------------------------------------------------------
// bf16-MFMA NT GEMM (bf16 out), BK=128 double-buffered LDS.
// ---------------------------------------------------------------------------
template<int BM, int BN, bool RELU, bool BIASC>
__global__ __launch_bounds__(256, 2)
void gemm_bf16(const unsigned short* __restrict__ A, int lda,
               const unsigned short* __restrict__ W, int ldw,
               const float* __restrict__ bias,
               unsigned short* __restrict__ Cout, int ldc, int K)
{
    constexpr int BK = 128, LDK = BK + 8;
    constexpr int SM = BM / 2, SN = BN / 2;
    constexpr int FM = SM / 16, FN = SN / 16;
    constexpr int AIT = BM / 16, WIT = BN / 16;
    __shared__ unsigned short As[2][BM][LDK];
    __shared__ unsigned short Bs[2][BN][LDK];

    const int tid  = threadIdx.x;
    const int row0 = blockIdx.x * BM, col0 = blockIdx.y * BN;
    const int wv = tid >> 6, lane = tid & 63;
    const int wr = wv >> 1, wc = wv & 1;
    const int lr = lane & 15, lq = lane >> 4;

    f32x4 acc[FM][FN];
#pragma unroll
    for (int i = 0; i < FM; ++i)
#pragma unroll
        for (int j = 0; j < FN; ++j) acc[i][j] = (f32x4)0.f;

    short8 pa[AIT], pw[WIT];
    auto issue = [&](int k0) {
#pragma unroll
        for (int i = 0; i < AIT; ++i) {
            const int idx = tid + i * 256, r = idx >> 4, c8 = idx & 15;
            pa[i] = *(const short8*)&A[(size_t)(row0 + r) * lda + k0 + c8 * 8];
        }
#pragma unroll
        for (int i = 0; i < WIT; ++i) {
            const int idx = tid + i * 256, r = idx >> 4, c8 = idx & 15;
            pw[i] = *(const short8*)&W[(size_t)(col0 + r) * ldw + k0 + c8 * 8];
        }
    };
    auto store = [&](int bsel) {
#pragma unroll
        for (int i = 0; i < AIT; ++i) {
            const int idx = tid + i * 256, r = idx >> 4, c8 = idx & 15;
            *(short8*)&As[bsel][r][c8 * 8] = pa[i];
        }
#pragma unroll
        for (int i = 0; i < WIT; ++i) {
            const int idx = tid + i * 256, r = idx >> 4, c8 = idx & 15;
            *(short8*)&Bs[bsel][r][c8 * 8] = pw[i];
        }
    };

    issue(0); store(0);
    const int NC = K / BK;
    for (int c = 0; c < NC; ++c) {
        const int buf = c & 1;
        __syncthreads();
        if (c + 1 < NC) issue((c + 1) * BK);
#pragma unroll
        for (int ks = 0; ks < BK / 32; ++ks) {
            short8 af[FM], bfr[FN];
#pragma unroll
            for (int i = 0; i < FM; ++i)
                af[i] = *(const short8*)&As[buf][wr * SM + i * 16 + lr][ks * 32 + lq * 8];
#pragma unroll
            for (int j = 0; j < FN; ++j)
                bfr[j] = *(const short8*)&Bs[buf][wc * SN + j * 16 + lr][ks * 32 + lq * 8];
#pragma unroll
            for (int i = 0; i < FM; ++i)
#pragma unroll
                for (int j = 0; j < FN; ++j)
                    acc[i][j] = __builtin_amdgcn_mfma_f32_16x16x32_bf16(
                        af[i], bfr[j], acc[i][j], 0, 0, 0);
        }
        if (c + 1 < NC) store((c + 1) & 1);
    }

#pragma unroll
    for (int i = 0; i < FM; ++i) {
#pragma unroll
        for (int j = 0; j < FN; ++j) {
            const int colb = col0 + wc * SN + j * 16 + lr;
#pragma unroll
            for (int e = 0; e < 4; ++e) {
                const int row = row0 + wr * SM + i * 16 + lq * 4 + e;
                float v = acc[i][j][e];
                if (BIASC) v += bias[colb];
                if (RELU)  v = fmaxf(v, 0.f);
                Cout[(size_t)row * ldc + colb] = f2bf(v);
            }
        }
    }
}

// ---------------------------------------------------------------------------
// Dual GEMM for hxT/cmT (f16 h-pair-packed out), BK=128 double-buffered.
// ---------------------------------------------------------------------------
__global__ __launch_bounds__(256, 2)
void gemm_pair(const unsigned short* __restrict__ W1x_bf,
               const unsigned short* __restrict__ W1t_bf,
               const unsigned short* __restrict__ x_emb_bf,
               const unsigned short* __restrict__ t_emb_bf,
               const float* __restrict__ b1,
               unsigned int* __restrict__ hxT_p,
               unsigned int* __restrict__ cmT_p)
{
    constexpr int BM = 32, BN = 64, BK = 128, LDK = BK + 8;
    constexpr int SM = 16, SN = 32, FN = 2;
    __shared__ unsigned short As[2][BM][LDK];
    __shared__ unsigned short Bs[2][BN][LDK];

    const unsigned short* A; const unsigned short* B;
    const float* bias; unsigned int* outp; int ldc, col0;
    if (blockIdx.y < 32) {
        A = W1x_bf; B = x_emb_bf; bias = nullptr; outp = hxT_p;
        ldc = N_; col0 = blockIdx.y * BN;
    } else {
        A = W1t_bf; B = t_emb_bf; bias = b1; outp = cmT_p;
        ldc = M_; col0 = (blockIdx.y - 32) * BN;
    }
    const int K = EMB, row0 = blockIdx.x * BM;

    const int tid = threadIdx.x;
    const int wv = tid >> 6, lane = tid & 63;
    const int wr = wv >> 1, wc = wv & 1;
    const int lr = lane & 15, lq = lane >> 4;

    f32x4 acc[FN];
#pragma unroll
    for (int j = 0; j < FN; ++j) acc[j] = (f32x4)0.f;

    short8 pa[2], pw[4];
    auto issue = [&](int k0) {
#pragma unroll
        for (int i = 0; i < 2; ++i) {
            const int idx = tid + i * 256, r = idx >> 4, c8 = idx & 15;
            pa[i] = *(const short8*)&A[(size_t)(row0 + r) * K + k0 + c8 * 8];
        }
#pragma unroll
        for (int i = 0; i < 4; ++i) {
            const int idx = tid + i * 256, r = idx >> 4, c8 = idx & 15;
            pw[i] = *(const short8*)&B[(size_t)(col0 + r) * K + k0 + c8 * 8];
        }
    };
    auto store = [&](int bsel) {
#pragma unroll
        for (int i = 0; i < 2; ++i) {
            const int idx = tid + i * 256, r = idx >> 4, c8 = idx & 15;
            *(short8*)&As[bsel][r][c8 * 8] = pa[i];
        }
#pragma unroll
        for (int i = 0; i < 4; ++i) {
            const int idx = tid + i * 256, r = idx >> 4, c8 = idx & 15;
            *(short8*)&Bs[bsel][r][c8 * 8] = pw[i];
        }
    };

    issue(0); store(0);
    const int NC = K / BK;  // 2
    for (int c = 0; c < NC; ++c) {
        const int buf = c & 1;
        __syncthreads();
        if (c + 1 < NC) issue((c + 1) * BK);
#pragma unroll
        for (int ks = 0; ks < BK / 32; ++ks) {
            short8 af, bfr[FN];
            af = *(const short8*)&As[buf][wr * SM + lr][ks * 32 + lq * 8];
#pragma unroll
            for (int j = 0; j < FN; ++j)
                bfr[j] = *(const short8*)&Bs[buf][wc * SN + j * 16 + lr][ks * 32 + lq * 8];
#pragma unroll
            for (int j = 0; j < FN; ++j)
                acc[j] = __builtin_amdgcn_mfma_f32_16x16x32_bf16(af, bfr[j], acc[j], 0, 0, 0);
        }
        if (c + 1 < NC) store((c + 1) & 1);
    }

    const int rowb = row0 + wr * SM + lq * 4;   // multiple of 4
#pragma unroll
    for (int j = 0; j < FN; ++j) {
        const int colb = col0 + wc * SN + j * 16 + lr;
#pragma unroll
        for (int e2 = 0; e2 < 2; ++e2) {
            float v0 = acc[j][2 * e2], v1 = acc[j][2 * e2 + 1];
            if (bias) { v0 += bias[rowb + 2 * e2]; v1 += bias[rowb + 2 * e2 + 1]; }
            outp[(size_t)((rowb >> 1) + e2) * ldc + colb] = packh2(v0, v1);
        }
    }
}

// ---------------------------------------------------------------------------
// part[z][n][m] (f16) = sum_{h2 in z} relu(hx_pair + cm_pair) . w2_pair
// z=8 split (H2B=32), tile 64n x 64m, 1024 blocks, LDS ~18 KB, LB(256,4)
// -> 4 blocks/CU (16 waves/CU). No atomics: f16 partials + reduce kernel.
// ---------------------------------------------------------------------------
__global__ __launch_bounds__(256, 4)
void fused_out(const unsigned int* __restrict__ hxT_p,   // [256][2048]
               const unsigned int* __restrict__ cmT_p,   // [256][256]
               const unsigned int* __restrict__ w2p,     // [256]
               unsigned int* __restrict__ part_u32)      // f16 [8][2048][256]
{
    constexpr int TN = 64, TM = 64, H2B = 32, LDT = 68;
    __shared__ unsigned int Hs[H2B][LDT];
    __shared__ unsigned int Cs[H2B][LDT];
    __shared__ unsigned int Wsh[H2B];

    const int tid = threadIdx.x;
    const int tx = tid & 15, ty = tid >> 4;
    const int n0 = blockIdx.x * TN;
    const int m0 = blockIdx.y * TM;
    const int kb = blockIdx.z * H2B;

#pragma unroll
    for (int p = 0; p < 2; ++p) {
        const int idx = tid + p * 256, r = idx >> 4, c4 = idx & 15;
        *(uint4*)&Hs[r][c4 * 4] =
            *(const uint4*)&hxT_p[(size_t)(kb + r) * N_ + n0 + c4 * 4];
        *(uint4*)&Cs[r][c4 * 4] =
            *(const uint4*)&cmT_p[(size_t)(kb + r) * M_ + m0 + c4 * 4];
    }
    if (tid < H2B) Wsh[tid] = w2p[kb + tid];
    __syncthreads();

    float acc[4][4];
#pragma unroll
    for (int i = 0; i < 4; ++i)
#pragma unroll
        for (int j = 0; j < 4; ++j) acc[i][j] = 0.f;

#ifdef HAVE_FDOT2
#pragma unroll 8
    for (int h = 0; h < H2B; ++h) {
        const uint4 av = *(const uint4*)&Hs[h][ty * 4];
        const uint4 bv = *(const uint4*)&Cs[h][tx * 4];
        U32H2 w; w.u = Wsh[h];
        U32H2 a[4], b[4];
        a[0].u = av.x; a[1].u = av.y; a[2].u = av.z; a[3].u = av.w;
        b[0].u = bv.x; b[1].u = bv.y; b[2].u = bv.z; b[3].u = bv.w;
#pragma unroll
        for (int i = 0; i < 4; ++i)
#pragma unroll
            for (int j = 0; j < 4; ++j) {
                const h2v s = relu2(a[i].v + b[j].v);
                acc[i][j] = __builtin_amdgcn_fdot2(s, w.v, acc[i][j], false);
            }
    }
#else
    U32H2 facc[4][4];
#pragma unroll
    for (int i = 0; i < 4; ++i)
#pragma unroll
        for (int j = 0; j < 4; ++j) facc[i][j].u = 0u;
#pragma unroll
    for (int hb = 0; hb < H2B / 8; ++hb) {
#pragma unroll
        for (int hh = 0; hh < 8; ++hh) {
            const int h = hb * 8 + hh;
            const uint4 av = *(const uint4*)&Hs[h][ty * 4];
            const uint4 bv = *(const uint4*)&Cs[h][tx * 4];
            U32H2 w; w.u = Wsh[h];
            U32H2 a[4], b[4];
            a[0].u = av.x; a[1].u = av.y; a[2].u = av.z; a[3].u = av.w;
            b[0].u = bv.x; b[1].u = bv.y; b[2].u = bv.z; b[3].u = bv.w;
#pragma unroll
            for (int i = 0; i < 4; ++i)
#pragma unroll
                for (int j = 0; j < 4; ++j) {
                    const h2v s = relu2(a[i].v + b[j].v);
                    facc[i][j].v = s * w.v + facc[i][j].v;
                }
        }
#pragma unroll
        for (int i = 0; i < 4; ++i)
#pragma unroll
            for (int j = 0; j < 4; ++j) {
                acc[i][j] += (float)facc[i][j].v[0] + (float)facc[i][j].v[1];
                facc[i][j].u = 0u;
            }
    }
#endif

    // write f16 partials: 4 n-rows x 2 m-pair-words per thread
#pragma unroll
    for (int i = 0; i < 4; ++i) {
        const int n = n0 + ty * 4 + i;
        const size_t base = ((size_t)blockIdx.z * N_ + n) * (M_ / 2) + (m0 >> 1) + tx * 2;
        part_u32[base]     = packh2(acc[i][0], acc[i][1]);
        part_u32[base + 1] = packh2(acc[i][2], acc[i][3]);
    }
}

// ---------------------------------------------------------------------------
// out[n,m] = b2 + sum_{z=0..7} part[z][n][m]
// ---------------------------------------------------------------------------
__global__ __launch_bounds__(256)
void reduce_out(const unsigned short* __restrict__ part,
                const float* __restrict__ b2,
                float* __restrict__ out)
{
    const int g = blockIdx.x * 256 + threadIdx.x;   // 65536
    const int n = g >> 5;
    const int m0 = (g & 31) * 8;
    const float bb = b2[0];
    float s[8];
#pragma unroll
    for (int i = 0; i < 8; ++i) s[i] = bb;
#pragma unroll
    for (int zz = 0; zz < 8; ++zz) {
        const uint4 v = *(const uint4*)&part[((size_t)zz * N_ + n) * M_ + m0];
        const unsigned int vv[4] = {v.x, v.y, v.z, v.w};
#pragma unroll
        for (int q = 0; q < 4; ++q) {
            U32H2 u; u.u = vv[q];
            s[2 * q]     += (float)u.v[0];
            s[2 * q + 1] += (float)u.v[1];
        }
    }
    float4 o0 = {s[0], s[1], s[2], s[3]};
    float4 o1 = {s[4], s[5], s[6], s[7]};
    *(float4*)&out[(size_t)n * M_ + m0]     = o0;
    *(float4*)&out[(size_t)n * M_ + m0 + 4] = o1;
}

// ---------------------------------------------------------------------------
extern "C" void kernel_launch(void* const* d_in, const int* in_sizes, int n_in,
                              void* d_out, int out_size, void* d_ws, size_t ws_size,
                              hipStream_t stream)
{
    const float* x      = (const float*)d_in[0];
    const int*   tuples = (const int*)d_in[1];
    const float* Wa     = (const float*)d_in[2];
    const float* ba     = (const float*)d_in[3];
    const float* Wb     = (const float*)d_in[4];
    const float* bb     = (const float*)d_in[5];
    const float* E_pred = (const float*)d_in[6];
    const float* E_filt = (const float*)d_in[7];
    const float* E_reo  = (const float*)d_in[8];
    const float* W1     = (const float*)d_in[9];
    const float* b1     = (const float*)d_in[10];
    const float* W2     = (const float*)d_in[11];
    const float* b2     = (const float*)d_in[12];
    float* out = (float*)d_out;

    // ws layout: generous disjoint regions (ws is 256+ MB, no overlays).
    char* w = (char*)d_ws;
    unsigned short* x_bf     = (unsigned short*)(w + (0 << 20));        // 2 MB
    unsigned short* h_x_bf   = (unsigned short*)(w + (2 << 20));        // 2 MB
    unsigned short* x_emb_bf = (unsigned short*)(w + (4 << 20));        // 1 MB
    unsigned short* Wa_bf    = (unsigned short*)(w + (5 << 20));        // 512 KB
    unsigned short* Wb_bf    = (unsigned short*)(w + (6 << 20));        // 256 KB
    unsigned short* W1x_bf   = (unsigned short*)(w + (7 << 20));        // 256 KB
    unsigned short* W1t_bf   = (unsigned short*)(w + (8 << 20));        // 256 KB
    unsigned short* t_emb_bf = (unsigned short*)(w + (9 << 20));        // 128 KB
    unsigned int*   w2p      = (unsigned int*)(w + (10 << 20));         // 1 KB
    unsigned int*   hxT_p    = (unsigned int*)(w + (12 << 20));         // 2 MB
    unsigned int*   cmT_p    = (unsigned int*)(w + (15 << 20));         // 256 KB
    unsigned int*   part_u32 = (unsigned int*)(w + (16 << 20));         // 8 MB

    prep<<<dim3(1729), dim3(256), 0, stream>>>(
        x, Wa, Wb, W1, tuples, E_pred, E_filt, E_reo, W2,
        x_bf, Wa_bf, Wb_bf, W1x_bf, W1t_bf, t_emb_bf, w2p);

    // h_x = relu(x @ Wa^T + ba)   (2048x512, K=512) grid 64x8
    gemm_bf16<32, 64, true, true><<<dim3(N_ / 32, HID / 64), 256, 0, stream>>>(
        x_bf, IN_DIM, Wa_bf, IN_DIM, ba, h_x_bf, HID, IN_DIM);

    // x_emb = relu(h_x @ Wb^T + bb)  (2048x256, K=512) grid 64x8
    gemm_bf16<32, 32, true, true><<<dim3(N_ / 32, EMB / 32), 256, 0, stream>>>(
        h_x_bf, HID, Wb_bf, HID, bb, x_emb_bf, EMB, HID);

    // hxT_p[h2][n] & cmT_p[h2][m] (f16 h-pairs), merged: grid 16 x (32+4)
    gemm_pair<<<dim3(HID / 32, 36), 256, 0, stream>>>(
        W1x_bf, W1t_bf, x_emb_bf, t_emb_bf, b1, hxT_p, cmT_p);

    // partials over z=8 h-slices, 64x64 tiles -> 1024 blocks
    fused_out<<<dim3(N_ / 64, M_ / 64, 8), 256, 0, stream>>>(
        hxT_p, cmT_p, w2p, part_u32);

    // out = b2 + sum_z part
    reduce_out<<<dim3(65536 / 256), 256, 0, stream>>>(
        (const unsigned short*)part_u32, b2, out);
}